// Round 2
// baseline (6415.984 us; speedup 1.0000x reference)
//
#include <hip/hip_runtime.h>
#include <hip/hip_fp16.h>

#define NNODE 10000
#define NEDGE 160000
#define WIDTH 32
#define KW 256
#define TILE_E 32
#define HPAD 36   // 36 floats = 144 B rows, 16B-aligned for float4 reads

// ---- edge kernel MLP for a chunk: edge_attr[e0..] -> W[(e-e_start),1024] fp16 ----
__global__ __launch_bounds__(256) void mlp_kernel(
    const float* __restrict__ ea,
    const float* __restrict__ k1w, const float* __restrict__ k1b,
    const float* __restrict__ k2w, const float* __restrict__ k2b,
    const float* __restrict__ k3w, const float* __restrict__ k3b,
    __half* __restrict__ W, int e_start)
{
    __shared__ float ea_s[TILE_E][8];
    __shared__ float hbuf[KW][HPAD];   // h1^T then h2^T  (rows=channel, cols=edge)
    const int t = threadIdx.x;
    const int eloc0 = blockIdx.x * TILE_E;       // chunk-local base
    const int e0 = e_start + eloc0;              // global edge base

    if (t < TILE_E * 6) {
        int e = t / 6, k = t % 6;
        ea_s[e][k] = ea[(size_t)(e0 + e) * 6 + k];
    }
    __syncthreads();

    // h1: thread t = channel
    {
        float b  = k1b[t];
        float w0 = k1w[0*KW + t], w1 = k1w[1*KW + t], w2 = k1w[2*KW + t];
        float w3 = k1w[3*KW + t], w4 = k1w[4*KW + t], w5 = k1w[5*KW + t];
        #pragma unroll
        for (int e = 0; e < TILE_E; ++e) {
            float v = b + ea_s[e][0]*w0 + ea_s[e][1]*w1 + ea_s[e][2]*w2
                        + ea_s[e][3]*w3 + ea_s[e][4]*w4 + ea_s[e][5]*w5;
            hbuf[t][e] = fmaxf(v, 0.f);
        }
    }
    __syncthreads();

    // h2
    float acc[TILE_E];
    {
        float b = k2b[t];
        #pragma unroll
        for (int e = 0; e < TILE_E; ++e) acc[e] = b;
        for (int c = 0; c < KW; ++c) {
            float w = k2w[c*KW + t];
            const float4* row = (const float4*)&hbuf[c][0];
            #pragma unroll
            for (int q = 0; q < TILE_E/4; ++q) {
                float4 h4 = row[q];
                acc[q*4+0] += h4.x * w; acc[q*4+1] += h4.y * w;
                acc[q*4+2] += h4.z * w; acc[q*4+3] += h4.w * w;
            }
        }
    }
    __syncthreads();               // all reads of h1 done before overwrite
    #pragma unroll
    for (int e = 0; e < TILE_E; ++e) hbuf[t][e] = fmaxf(acc[e], 0.f);
    __syncthreads();

    // W = h2 @ k3_w + k3_b, 4 column groups of 256
    for (int og = 0; og < 4; ++og) {
        int o = og * 256 + t;
        float b = k3b[o];
        #pragma unroll
        for (int e = 0; e < TILE_E; ++e) acc[e] = b;
        for (int c = 0; c < KW; ++c) {
            float w = k3w[(size_t)c * 1024 + o];
            const float4* row = (const float4*)&hbuf[c][0];
            #pragma unroll
            for (int q = 0; q < TILE_E/4; ++q) {
                float4 h4 = row[q];
                acc[q*4+0] += h4.x * w; acc[q*4+1] += h4.y * w;
                acc[q*4+2] += h4.z * w; acc[q*4+3] += h4.w * w;
            }
        }
        #pragma unroll
        for (int e = 0; e < TILE_E; ++e)
            W[(size_t)(eloc0 + e) * 1024 + o] = __float2half(acc[e]);
    }
}

// ---- h0 = x @ fc1_w + fc1_b ----
__global__ __launch_bounds__(256) void h0_kernel(
    const float* __restrict__ x, const float* __restrict__ fc1w,
    const float* __restrict__ fc1b, float* __restrict__ h)
{
    int idx = blockIdx.x * 256 + threadIdx.x;   // N*32 exact
    int n = idx >> 5, j = idx & 31;
    h[idx] = x[n] * fc1w[j] + fc1b[j];
}

// ---- degree via atomics ----
__global__ __launch_bounds__(256) void deg_kernel(
    const int* __restrict__ ei, float* __restrict__ deg)
{
    int e = blockIdx.x * 256 + threadIdx.x;
    if (e < NEDGE) atomicAdd(&deg[ei[NEDGE + e]], 1.f);
}

// ---- msg for a chunk: h[src] @ W_e, scatter-add ----
__global__ __launch_bounds__(256) void msg_kernel(
    const int* __restrict__ ei, const __half* __restrict__ W,
    const float* __restrict__ h, float* __restrict__ agg, int e_start)
{
    const int t = threadIdx.x;
    const int el = t >> 5, o = t & 31;
    const int eloc = blockIdx.x * 8 + el;
    const int e = e_start + eloc;
    const int src = ei[e];
    const int dst = ei[NEDGE + e];
    float hv = h[src * WIDTH + o];
    const __half* We = W + (size_t)eloc * 1024;
    float acc = 0.f;
    #pragma unroll
    for (int i = 0; i < WIDTH; ++i) {
        float hi = __shfl(hv, i, 32);
        acc += hi * __half2float(We[i * WIDTH + o]);
    }
    atomicAdd(&agg[dst * WIDTH + o], acc);
}

// ---- node update ----
__global__ __launch_bounds__(256) void update_kernel(
    const float* __restrict__ h_old, float* __restrict__ h_new,
    float* __restrict__ agg, const float* __restrict__ deg,
    const float* __restrict__ rootw, const float* __restrict__ convb)
{
    __shared__ float rw[WIDTH][WIDTH + 1];
    const int t = threadIdx.x;
    for (int q = t; q < WIDTH * WIDTH; q += 256)
        rw[q >> 5][q & 31] = rootw[q];
    __syncthreads();
    const int nl = t >> 5, j = t & 31;
    const int n = blockIdx.x * 8 + nl;
    float hv = h_old[n * WIDTH + j];
    float acc = convb[j];
    #pragma unroll
    for (int k = 0; k < WIDTH; ++k)
        acc += __shfl(hv, k, 32) * rw[k][j];
    float inv = 1.f / fmaxf(deg[n], 1.f);
    int idx = n * WIDTH + j;
    float a = agg[idx];
    agg[idx] = 0.f;               // re-zero for next depth
    h_new[idx] = fmaxf(a * inv + acc, 0.f);
}

// ---- out = h @ fc2_w + fc2_b ----
__global__ __launch_bounds__(256) void out_kernel(
    const float* __restrict__ h, const float* __restrict__ fc2w,
    const float* __restrict__ fc2b, float* __restrict__ out)
{
    int n = blockIdx.x * 256 + threadIdx.x;
    if (n < NNODE) {
        float a = fc2b[0];
        #pragma unroll
        for (int j = 0; j < WIDTH; ++j)
            a += h[n * WIDTH + j] * fc2w[j];
        out[n] = a;
    }
}

extern "C" void kernel_launch(void* const* d_in, const int* in_sizes, int n_in,
                              void* d_out, int out_size, void* d_ws, size_t ws_size,
                              hipStream_t stream) {
    const float* x    = (const float*)d_in[0];
    const int*   ei   = (const int*)  d_in[1];
    const float* ea   = (const float*)d_in[2];
    const float* fc1w = (const float*)d_in[3];
    const float* fc1b = (const float*)d_in[4];
    const float* k1w  = (const float*)d_in[5];
    const float* k1b  = (const float*)d_in[6];
    const float* k2w  = (const float*)d_in[7];
    const float* k2b  = (const float*)d_in[8];
    const float* k3w  = (const float*)d_in[9];
    const float* k3b  = (const float*)d_in[10];
    const float* rootw= (const float*)d_in[11];
    const float* convb= (const float*)d_in[12];
    const float* fc2w = (const float*)d_in[13];
    const float* fc2b = (const float*)d_in[14];
    float* out = (float*)d_out;

    // ---- adaptive workspace layout: small fixed buffers first, W chunk after ----
    const size_t hbytes = (size_t)NNODE * WIDTH * 4;          // 1,280,000
    const size_t fixed  = 3 * hbytes + (((size_t)NNODE * 4 + 255) & ~(size_t)255);
    char* ws = (char*)d_ws;
    float*  hA  = (float*)ws;
    float*  hB  = (float*)(ws + hbytes);
    float*  agg = (float*)(ws + 2 * hbytes);
    float*  deg = (float*)(ws + 3 * hbytes);
    __half* W   = (__half*)(ws + fixed);

    long long availC = 0;
    if (ws_size > fixed) availC = (long long)((ws_size - fixed) / 2048);  // 1024 fp16 per edge
    int C = (availC > NEDGE) ? NEDGE : (int)availC;
    C &= ~31;                      // multiple of TILE_E
    if (C < 32) return;            // workspace too small: clean failure, no fault

    hipMemsetAsync(deg, 0, (size_t)NNODE * 4, stream);
    hipMemsetAsync(agg, 0, (size_t)NNODE * WIDTH * 4, stream);

    h0_kernel<<<NNODE * WIDTH / 256, 256, 0, stream>>>(x, fc1w, fc1b, hA);
    deg_kernel<<<(NEDGE + 255) / 256, 256, 0, stream>>>(ei, deg);

    const bool full = (C == NEDGE);
    if (full)  // W fits entirely: compute once, reuse across depth
        mlp_kernel<<<NEDGE / TILE_E, 256, 0, stream>>>(ea, k1w, k1b, k2w, k2b, k3w, k3b, W, 0);

    float* hcur = hA; float* hnext = hB;
    for (int d = 0; d < 4; ++d) {
        for (int es = 0; es < NEDGE; es += C) {
            int ce = (NEDGE - es < C) ? (NEDGE - es) : C;   // multiple of 32
            if (!full)
                mlp_kernel<<<ce / TILE_E, 256, 0, stream>>>(ea, k1w, k1b, k2w, k2b, k3w, k3b, W, es);
            msg_kernel<<<ce / 8, 256, 0, stream>>>(ei, W, hcur, agg, es);
        }
        update_kernel<<<NNODE / 8, 256, 0, stream>>>(hcur, hnext, agg, deg, rootw, convb);
        float* tmp = hcur; hcur = hnext; hnext = tmp;
    }
    out_kernel<<<(NNODE + 255) / 256, 256, 0, stream>>>(hcur, fc2w, fc2b, out);
}